// Round 7
// baseline (303.827 us; speedup 1.0000x reference)
//
#include <hip/hip_runtime.h>
#include <math.h>

#define VV 50257
#define VPAD 50304   // 393 * 128
#define DD 128
#define BB 1024
#define CC 10
#define NLSE 1572    // 393*4 k_lse blocks

typedef short bf16x8 __attribute__((ext_vector_type(8)));
typedef float f32x4 __attribute__((ext_vector_type(4)));

__device__ inline float bf2f(unsigned short u) {
    return __uint_as_float(((unsigned)u) << 16);
}
__device__ inline unsigned short f2bf(float f) {
    unsigned u = __float_as_uint(f);
    unsigned r = ((u >> 16) & 1) + 0x7FFF;
    return (unsigned short)((u + r) >> 16);
}

// Fragment-packed operand layout: chunk = (group*NKI + kI)*64 + quad*16 + l15,
// each chunk = 8 bf16 (16B); row group*16+l15, k = kI*32+quad*8+e.

// ---------------------------------------------------------------------------
// Kernel P: blocks 0..785: W_vocab -> WvP packed bf16 (pad rows zero).
//           blocks 786..801: W_enc -> WeP packed bf16.
//           blocks 802..805: W_mean/W_var -> Wmv interleaved bf16 pairs.
// ---------------------------------------------------------------------------
__global__ __launch_bounds__(256) void k_prep(
    const float* __restrict__ Wv, const float* __restrict__ W_enc,
    const float* __restrict__ W_mean, const float* __restrict__ W_var,
    unsigned short* __restrict__ WvP, unsigned short* __restrict__ WeP,
    unsigned short* __restrict__ Wmv)
{
    const int bid = blockIdx.x, tid = threadIdx.x;

    if (bid < 786) {
        __shared__ float tile[128][65];
        const int v0 = bid * 64;
#pragma unroll
        for (int i = 0; i < 32; ++i) {
            int idx = tid + i * 256;
            int k = idx >> 6, j = idx & 63;
            int v = v0 + j;
            tile[k][j] = (v < VV) ? Wv[(size_t)k * VV + v] : 0.f;
        }
        __syncthreads();
#pragma unroll
        for (int i = 0; i < 4; ++i) {
            int c = i * 256 + tid;
            int l15 = c & 15, q = (c >> 4) & 3, kI = (c >> 6) & 3, g = c >> 8;
            bf16x8 o;
#pragma unroll
            for (int e = 0; e < 8; ++e)
                o[e] = (short)f2bf(tile[kI * 32 + q * 8 + e][g * 16 + l15]);
            size_t vg = (size_t)bid * 4 + g;
            *(bf16x8*)(WvP + ((vg * 4 + kI) * 64 + q * 16 + l15) * 8) = o;
        }
        return;
    }

    if (bid < 802) {
        // W_enc pack: block jg handles output cols jg*16..+15, all 256 k.
        __shared__ float tl[256][17];
        const int jg = bid - 786;
#pragma unroll
        for (int i = 0; i < 16; ++i) {
            int idx = i * 256 + tid;
            int k = idx >> 4, j = idx & 15;
            tl[k][j] = W_enc[(size_t)k * 256 + jg * 16 + j];
        }
        __syncthreads();
#pragma unroll
        for (int i = 0; i < 2; ++i) {
            int c = i * 256 + tid;
            int l15 = c & 15, q = (c >> 4) & 3, kI = c >> 6;
            bf16x8 o;
#pragma unroll
            for (int e = 0; e < 8; ++e)
                o[e] = (short)f2bf(tl[kI * 32 + q * 8 + e][l15]);
            *(bf16x8*)(WeP + (((size_t)jg * 8 + kI) * 64 + q * 16 + l15) * 8) = o;
        }
        return;
    }

    // Wmv interleave: Wmv[(k*128+d)*2] = bf16(W_mean), +1 = bf16(W_var)
    const int b4 = bid - 802;
#pragma unroll
    for (int i = 0; i < 32; ++i) {
        int idx = b4 * 8192 + i * 256 + tid;
        unsigned short m = f2bf(W_mean[idx]);
        unsigned short v = f2bf(W_var[idx]);
        *(ushort2*)(Wmv + (size_t)idx * 2) = make_ushort2(m, v);
    }
}

// ---------------------------------------------------------------------------
// Kernel 1: encoder MFMA. Grid (16 b-tiles of 64, 10 c, 2 n-tiles).
// A staged in LDS fragment-packed (rows padded to 520 shorts: 4-way max
// store conflict); B from WeP; C transposed via LDS -> contiguous writes.
// ---------------------------------------------------------------------------
#define AS_STRIDE 520
__global__ __launch_bounds__(256) void k_enc(
    const int* __restrict__ center_id, const int* __restrict__ context_ids,
    const float* __restrict__ emb, const unsigned short* __restrict__ WeP,
    const float* __restrict__ b_enc, unsigned short* __restrict__ enc_relu)
{
    __shared__ __align__(16) unsigned short As[32 * AS_STRIDE];
    __shared__ __align__(16) unsigned short Cs[64][136];
    const int tid  = threadIdx.x;
    const int lane = tid & 63;
    const int wid  = tid >> 6;
    const int wm   = wid & 1;
    const int wn   = wid >> 1;
    const int quad = lane >> 4;
    const int l15  = lane & 15;

    const int b0 = blockIdx.x * 64;
    const int c  = blockIdx.y;
    const int n0 = blockIdx.z * 128;

    const int rlane = tid >> 4;       // 0..15
    const int c8    = tid & 15;       // k-chunk (8 k's)
    const int kIc   = c8 >> 2, qc = c8 & 3;
#pragma unroll
    for (int p = 0; p < 4; ++p) {
        int r = p * 16 + rlane;
        int rid_ce = center_id[b0 + r];
        int rid_cx = context_ids[(b0 + r) * CC + c];
        const float* s0 = emb + (size_t)rid_ce * 128 + c8 * 8;
        const float* s1 = emb + (size_t)rid_cx * 128 + c8 * 8;
        float4 a0 = *(const float4*)s0, a1 = *(const float4*)(s0 + 4);
        float4 b0v = *(const float4*)s1, b1v = *(const float4*)(s1 + 4);
        bf16x8 oa, ob;
        oa[0] = (short)f2bf(a0.x); oa[1] = (short)f2bf(a0.y);
        oa[2] = (short)f2bf(a0.z); oa[3] = (short)f2bf(a0.w);
        oa[4] = (short)f2bf(a1.x); oa[5] = (short)f2bf(a1.y);
        oa[6] = (short)f2bf(a1.z); oa[7] = (short)f2bf(a1.w);
        ob[0] = (short)f2bf(b0v.x); ob[1] = (short)f2bf(b0v.y);
        ob[2] = (short)f2bf(b0v.z); ob[3] = (short)f2bf(b0v.w);
        ob[4] = (short)f2bf(b1v.x); ob[5] = (short)f2bf(b1v.y);
        ob[6] = (short)f2bf(b1v.z); ob[7] = (short)f2bf(b1v.w);
        *(bf16x8*)(As + (size_t)(p * 8 + kIc) * AS_STRIDE + (qc * 16 + rlane) * 8) = oa;
        *(bf16x8*)(As + (size_t)(p * 8 + kIc + 4) * AS_STRIDE + (qc * 16 + rlane) * 8) = ob;
    }
    __syncthreads();

    float benc[4];
#pragma unroll
    for (int nt = 0; nt < 4; ++nt)
        benc[nt] = b_enc[n0 + wn * 64 + nt * 16 + l15];

    f32x4 acc[2][4];
#pragma unroll
    for (int mt = 0; mt < 2; ++mt)
#pragma unroll
        for (int nt = 0; nt < 4; ++nt) acc[mt][nt] = (f32x4){0.f, 0.f, 0.f, 0.f};

#pragma unroll
    for (int kI = 0; kI < 8; ++kI) {
        bf16x8 a[2], b[4];
#pragma unroll
        for (int mt = 0; mt < 2; ++mt)
            a[mt] = *(const bf16x8*)(As + (size_t)((wm * 2 + mt) * 8 + kI) * AS_STRIDE + lane * 8);
#pragma unroll
        for (int nt = 0; nt < 4; ++nt) {
            size_t jg = (size_t)blockIdx.z * 8 + wn * 4 + nt;
            b[nt] = *(const bf16x8*)(WeP + ((jg * 8 + kI) * 64 + lane) * 8);
        }
#pragma unroll
        for (int mt = 0; mt < 2; ++mt)
#pragma unroll
            for (int nt = 0; nt < 4; ++nt)
                acc[mt][nt] = __builtin_amdgcn_mfma_f32_16x16x32_bf16(
                    a[mt], b[nt], acc[mt][nt], 0, 0, 0);
    }

#pragma unroll
    for (int mt = 0; mt < 2; ++mt)
#pragma unroll
        for (int nt = 0; nt < 4; ++nt) {
            int col = wn * 64 + nt * 16 + l15;
#pragma unroll
            for (int reg = 0; reg < 4; ++reg) {
                int row = wm * 32 + mt * 16 + quad * 4 + reg;
                Cs[row][col] = f2bf(fmaxf(acc[mt][nt][reg] + benc[nt], 0.f));
            }
        }
    __syncthreads();
#pragma unroll
    for (int i = 0; i < 4; ++i) {
        int ch = i * 256 + tid;
        int row = ch >> 4, cc = ch & 15;
        bf16x8 v = *(const bf16x8*)&Cs[row][cc * 8];
        *(bf16x8*)(enc_relu + ((size_t)(b0 + row) * CC + c) * 256 + n0 + cc * 8) = v;
    }
}

// ---------------------------------------------------------------------------
// Kernel 2: latent heads + KL + context logits fused. 1024 blocks x 128 thr.
// Head weights from interleaved bf16 Wmv (one ushort2 per k). Writes z_pack
// and base[b] = ctxsum - kl. Zeroes sumexp[b] and the k_lse counter.
// ---------------------------------------------------------------------------
__global__ __launch_bounds__(128) void k_latent(
    const unsigned short* __restrict__ enc_relu, const unsigned short* __restrict__ Wmv,
    const float* __restrict__ b_mean, const float* __restrict__ b_var,
    const float* __restrict__ epsilon,
    const int* __restrict__ center_id, const int* __restrict__ context_ids,
    const unsigned short* __restrict__ WvP, const float* __restrict__ bv,
    const float* __restrict__ prior_means, const float* __restrict__ prior_vars,
    unsigned short* __restrict__ z_pack, float* __restrict__ base,
    float* __restrict__ sumexp, int* __restrict__ counter)
{
    __shared__ __align__(16) float hs[256];
    __shared__ float red[2];
    __shared__ float credp[CC][2];
    const int tid = threadIdx.x;
    const int b = blockIdx.x;
    const int wid = tid >> 6;

    if (tid == 0) {
        sumexp[b] = 0.f;
        if (b == 0) *counter = 0;
    }

    {
        const int j = tid * 2;
        float s0 = 0.f, s1 = 0.f;
#pragma unroll
        for (int c = 0; c < CC; ++c) {
            ushort2 u = *(const ushort2*)(enc_relu + ((size_t)b * CC + c) * 256 + j);
            s0 += bf2f(u.x); s1 += bf2f(u.y);
        }
        hs[j] = s0; hs[j + 1] = s1;
    }
    __syncthreads();

    const int d = tid;
    float m  = b_mean[d];
    float vr = b_var[d];
    for (int k0 = 0; k0 < 256; k0 += 4) {
        float4 h4 = *(const float4*)&hs[k0];
#pragma unroll
        for (int kk = 0; kk < 4; ++kk) {
            float hk = ((const float*)&h4)[kk];
            ushort2 u = *(const ushort2*)(Wmv + ((size_t)(k0 + kk) * 128 + d) * 2);
            m  += hk * bf2f(u.x);
            vr += hk * bf2f(u.y);
        }
    }

    float var = (vr > 20.f) ? vr : log1pf(__expf(vr));
    float zd = m + __expf(0.5f * var) * epsilon[d];
    unsigned short zu = f2bf(zd);
    const int kIz = d >> 5, qz = (d >> 3) & 3, ez = d & 7;
    {
        const int bg = b >> 4, l15b = b & 15;
        z_pack[(((size_t)(bg * 4 + kIz)) * 64 + qz * 16 + l15b) * 8 + ez] = zu;
    }
    float zb = bf2f(zu);

    int cid = center_id[b];
    float pm  = prior_means[(size_t)cid * 128 + d];
    float pvr = prior_vars[(size_t)cid * 128 + d];
    float pv  = (pvr > 20.f) ? pvr : log1pf(__expf(pvr));
    float diff = pm - m;
    float t = var / pv + diff * diff / pv - 1.f + logf(pv) - logf(var);
#pragma unroll
    for (int off = 32; off; off >>= 1) t += __shfl_down(t, off, 64);
    if ((tid & 63) == 0) red[wid] = t;

    int cids[CC];
#pragma unroll
    for (int p = 0; p < CC; ++p) cids[p] = context_ids[b * CC + p];
    float cs[CC];
#pragma unroll
    for (int p = 0; p < CC; ++p) {
        int vg = cids[p] >> 4, l15v = cids[p] & 15;
        float w = bf2f(WvP[(((size_t)(vg * 4 + kIz)) * 64 + qz * 16 + l15v) * 8 + ez]);
        cs[p] = zb * w;
    }
#pragma unroll
    for (int p = 0; p < CC; ++p) {
#pragma unroll
        for (int off = 32; off; off >>= 1) cs[p] += __shfl_down(cs[p], off, 64);
    }
    if ((tid & 63) == 0) {
#pragma unroll
        for (int p = 0; p < CC; ++p) credp[p][wid] = cs[p];
    }
    __syncthreads();
    if (tid == 0) {
        float klv = 0.5f * (red[0] + red[1]);
        float c = 0.f;
#pragma unroll
        for (int p = 0; p < CC; ++p)
            c += credp[p][0] + credp[p][1] + bv[cids[p]];
        base[b] = c - klv;
    }
}

// ---------------------------------------------------------------------------
// Kernel 3: streaming MFMA GEMM + exp-sum + FUSED final reduction.
// Grid (393, 4); block = 128 vocab x 256 batch. Per-row exp sums go to
// global sumexp via atomicAdd; last block (device counter) computes
// out[0] = mean(base - 10*log(sumexp)).
// ---------------------------------------------------------------------------
__global__ __launch_bounds__(256) void k_lse(
    const unsigned short* __restrict__ z_pack, const unsigned short* __restrict__ WvP,
    const float* __restrict__ bv, const float* __restrict__ base,
    float* __restrict__ sumexp, int* __restrict__ counter,
    float* __restrict__ out)
{
    __shared__ float pl[2][128][20];
    __shared__ float fred[4];
    __shared__ int isLast;
    const int tid  = threadIdx.x;
    const int lane = tid & 63;
    const int wid  = tid >> 6;
    const int wm   = wid & 1;
    const int wn   = wid >> 1;
    const int quad = lane >> 4;
    const int l15  = lane & 15;
    const int n0   = blockIdx.x * 128;
    const int mg   = blockIdx.y;       // 0..3

    bf16x8 bfr[4][4];
#pragma unroll
    for (int nt = 0; nt < 4; ++nt) {
        size_t vg = (size_t)blockIdx.x * 8 + wn * 4 + nt;
#pragma unroll
        for (int kI = 0; kI < 4; ++kI)
            bfr[nt][kI] = *(const bf16x8*)(WvP + ((vg * 4 + kI) * 64 + lane) * 8);
    }

    float bvf[4];
#pragma unroll
    for (int nt = 0; nt < 4; ++nt) {
        int n = n0 + wn * 64 + nt * 16 + l15;
        bvf[nt] = (n < VV) ? bv[n] : -__builtin_huge_valf();
    }

#pragma unroll
    for (int mi = 0; mi < 2; ++mi) {
        const int mi_g = mg * 2 + mi;        // 0..7

        f32x4 acc[4][4];
#pragma unroll
        for (int mt = 0; mt < 4; ++mt)
#pragma unroll
            for (int nt = 0; nt < 4; ++nt) acc[mt][nt] = (f32x4){0.f, 0.f, 0.f, 0.f};

#pragma unroll
        for (int kI = 0; kI < 4; ++kI) {
            bf16x8 afr[4];
#pragma unroll
            for (int mt = 0; mt < 4; ++mt) {
                size_t bg = (size_t)mi_g * 8 + wm * 4 + mt;
                afr[mt] = *(const bf16x8*)(z_pack + ((bg * 4 + kI) * 64 + lane) * 8);
            }
#pragma unroll
            for (int mt = 0; mt < 4; ++mt)
#pragma unroll
                for (int nt = 0; nt < 4; ++nt)
                    acc[mt][nt] = __builtin_amdgcn_mfma_f32_16x16x32_bf16(
                        afr[mt], bfr[nt][kI], acc[mt][nt], 0, 0, 0);
        }

#pragma unroll
        for (int mt = 0; mt < 4; ++mt)
#pragma unroll
            for (int reg = 0; reg < 4; ++reg) {
                float s = 0.f;
#pragma unroll
                for (int nt = 0; nt < 4; ++nt)
                    s += __expf(acc[mt][nt][reg] + bvf[nt]);
                pl[wn][wm * 64 + mt * 16 + quad * 4 + reg][l15] = s;
            }
        __syncthreads();
        if (tid < 128) {
            const float* p0 = &pl[0][tid][0];
            const float* p1 = &pl[1][tid][0];
            float4 a0 = *(const float4*)(p0);
            float4 a1 = *(const float4*)(p0 + 4);
            float4 a2 = *(const float4*)(p0 + 8);
            float4 a3 = *(const float4*)(p0 + 12);
            float4 b0 = *(const float4*)(p1);
            float4 b1 = *(const float4*)(p1 + 4);
            float4 b2 = *(const float4*)(p1 + 8);
            float4 b3 = *(const float4*)(p1 + 12);
            float tot = (a0.x + a0.y + a0.z + a0.w) + (a1.x + a1.y + a1.z + a1.w)
                      + (a2.x + a2.y + a2.z + a2.w) + (a3.x + a3.y + a3.z + a3.w)
                      + (b0.x + b0.y + b0.z + b0.w) + (b1.x + b1.y + b1.z + b1.w)
                      + (b2.x + b2.y + b2.z + b2.w) + (b3.x + b3.y + b3.z + b3.w);
            atomicAdd(&sumexp[mi_g * 128 + tid], tot);
        }
        __syncthreads();
    }

    // ---- last-block final reduction ----
    __threadfence();
    if (tid == 0) {
        int prev = atomicAdd(counter, 1);
        isLast = (prev == NLSE - 1);
    }
    __syncthreads();
    if (!isLast) return;
    __threadfence();

    const volatile float* sv = sumexp;
    float s = 0.f;
    for (int i = tid; i < 1024; i += 256)
        s += base[i] - 10.f * logf(sv[i]);
#pragma unroll
    for (int off = 32; off; off >>= 1) s += __shfl_down(s, off, 64);
    if ((tid & 63) == 0) fred[tid >> 6] = s;
    __syncthreads();
    if (tid == 0)
        out[0] = (fred[0] + fred[1] + fred[2] + fred[3]) * (1.f / 1024.f);
}

// ---------------------------------------------------------------------------
extern "C" void kernel_launch(void* const* d_in, const int* in_sizes, int n_in,
                              void* d_out, int out_size, void* d_ws, size_t ws_size,
                              hipStream_t stream)
{
    const int*   center_id   = (const int*)d_in[0];
    const int*   context_ids = (const int*)d_in[1];
    const float* epsilon     = (const float*)d_in[2];
    const float* emb         = (const float*)d_in[3];
    const float* prior_means = (const float*)d_in[4];
    const float* prior_vars  = (const float*)d_in[5];
    const float* W_enc       = (const float*)d_in[6];
    const float* b_enc       = (const float*)d_in[7];
    const float* W_mean      = (const float*)d_in[8];
    const float* b_mean      = (const float*)d_in[9];
    const float* W_var       = (const float*)d_in[10];
    const float* b_var       = (const float*)d_in[11];
    const float* W_vocab     = (const float*)d_in[12];
    const float* b_vocab     = (const float*)d_in[13];

    float* out = (float*)d_out;
    char*  ws  = (char*)d_ws;

    size_t off = 0;
    unsigned short* WvP      = (unsigned short*)(ws + off); off += 12877824;  // 50304*128*2
    unsigned short* WeP      = (unsigned short*)(ws + off); off += 131072;    // 256*256*2
    unsigned short* Wmv      = (unsigned short*)(ws + off); off += 131072;    // 256*128*2*2
    unsigned short* z_pack   = (unsigned short*)(ws + off); off += 262144;    // 1024*128*2
    unsigned short* enc_relu = (unsigned short*)(ws + off); off += 5242880;   // 1024*10*256*2
    float*          base     = (float*)(ws + off);          off += 4096;
    float*          sumexp   = (float*)(ws + off);          off += 4096;
    int*            counter  = (int*)(ws + off);            off += 64;

    k_prep<<<806, 256, 0, stream>>>(W_vocab, W_enc, W_mean, W_var, WvP, WeP, Wmv);
    k_enc<<<dim3(16, 10, 2), 256, 0, stream>>>(center_id, context_ids, emb, WeP,
                                               b_enc, enc_relu);
    k_latent<<<1024, 128, 0, stream>>>(enc_relu, Wmv, b_mean, b_var, epsilon,
                                       center_id, context_ids, WvP, b_vocab,
                                       prior_means, prior_vars, z_pack, base,
                                       sumexp, counter);
    k_lse<<<dim3(393, 4), 256, 0, stream>>>(z_pack, WvP, b_vocab, base,
                                            sumexp, counter, out);
}

// Round 8
// 208.212 us; speedup vs baseline: 1.4592x; 1.4592x over previous
//
#include <hip/hip_runtime.h>
#include <math.h>

#define VV 50257
#define VPAD 50304   // 393 * 128
#define DD 128
#define BB 1024
#define CC 10

typedef short bf16x8 __attribute__((ext_vector_type(8)));
typedef float f32x4 __attribute__((ext_vector_type(4)));

__device__ inline float bf2f(unsigned short u) {
    return __uint_as_float(((unsigned)u) << 16);
}
__device__ inline unsigned short f2bf(float f) {
    unsigned u = __float_as_uint(f);
    unsigned r = ((u >> 16) & 1) + 0x7FFF;
    return (unsigned short)((u + r) >> 16);
}

// Fragment-packed operand layout: chunk = (group*NKI + kI)*64 + quad*16 + l15,
// each chunk = 8 bf16 (16B); row group*16+l15, k = kI*32+quad*8+e.
// Every MFMA operand load is then 64 lanes x 16B contiguous (1KB dwordx4).

// ---------------------------------------------------------------------------
// Kernel P: blocks 0..785: W_vocab -> WvP packed bf16 (pad rows zero).
//           blocks 786..801: W_enc -> WeP packed bf16.
//           blocks 802..805: W_mean/W_var -> Wmv interleaved bf16 pairs.
// ---------------------------------------------------------------------------
__global__ __launch_bounds__(256) void k_prep(
    const float* __restrict__ Wv, const float* __restrict__ W_enc,
    const float* __restrict__ W_mean, const float* __restrict__ W_var,
    unsigned short* __restrict__ WvP, unsigned short* __restrict__ WeP,
    unsigned short* __restrict__ Wmv)
{
    const int bid = blockIdx.x, tid = threadIdx.x;

    if (bid < 786) {
        __shared__ float tile[128][65];
        const int v0 = bid * 64;
#pragma unroll
        for (int i = 0; i < 32; ++i) {
            int idx = tid + i * 256;
            int k = idx >> 6, j = idx & 63;
            int v = v0 + j;
            tile[k][j] = (v < VV) ? Wv[(size_t)k * VV + v] : 0.f;
        }
        __syncthreads();
#pragma unroll
        for (int i = 0; i < 4; ++i) {
            int c = i * 256 + tid;
            int l15 = c & 15, q = (c >> 4) & 3, kI = (c >> 6) & 3, g = c >> 8;
            bf16x8 o;
#pragma unroll
            for (int e = 0; e < 8; ++e)
                o[e] = (short)f2bf(tile[kI * 32 + q * 8 + e][g * 16 + l15]);
            size_t vg = (size_t)bid * 4 + g;
            *(bf16x8*)(WvP + ((vg * 4 + kI) * 64 + q * 16 + l15) * 8) = o;
        }
        return;
    }

    if (bid < 802) {
        // W_enc pack: block jg handles output cols jg*16..+15, all 256 k.
        __shared__ float tl[256][17];
        const int jg = bid - 786;
#pragma unroll
        for (int i = 0; i < 16; ++i) {
            int idx = i * 256 + tid;
            int k = idx >> 4, j = idx & 15;
            tl[k][j] = W_enc[(size_t)k * 256 + jg * 16 + j];
        }
        __syncthreads();
#pragma unroll
        for (int i = 0; i < 2; ++i) {
            int c = i * 256 + tid;
            int l15 = c & 15, q = (c >> 4) & 3, kI = c >> 6;
            bf16x8 o;
#pragma unroll
            for (int e = 0; e < 8; ++e)
                o[e] = (short)f2bf(tl[kI * 32 + q * 8 + e][l15]);
            *(bf16x8*)(WeP + (((size_t)jg * 8 + kI) * 64 + q * 16 + l15) * 8) = o;
        }
        return;
    }

    // Wmv interleave: Wmv[(k*128+d)*2] = bf16(W_mean), +1 = bf16(W_var)
    const int b4 = bid - 802;
#pragma unroll
    for (int i = 0; i < 32; ++i) {
        int idx = b4 * 8192 + i * 256 + tid;
        unsigned short m = f2bf(W_mean[idx]);
        unsigned short v = f2bf(W_var[idx]);
        *(ushort2*)(Wmv + (size_t)idx * 2) = make_ushort2(m, v);
    }
}

// ---------------------------------------------------------------------------
// Kernel 1: encoder MFMA. Grid (16 b-tiles of 64, 10 c, 2 n-tiles).
// A staged in LDS fragment-packed (rows padded to 520 shorts); B from WeP;
// C transposed via LDS -> contiguous bf16 writes to enc[b][c][j].
// ---------------------------------------------------------------------------
#define AS_STRIDE 520
__global__ __launch_bounds__(256) void k_enc(
    const int* __restrict__ center_id, const int* __restrict__ context_ids,
    const float* __restrict__ emb, const unsigned short* __restrict__ WeP,
    const float* __restrict__ b_enc, unsigned short* __restrict__ enc_relu)
{
    __shared__ __align__(16) unsigned short As[32 * AS_STRIDE];
    __shared__ __align__(16) unsigned short Cs[64][136];
    const int tid  = threadIdx.x;
    const int lane = tid & 63;
    const int wid  = tid >> 6;
    const int wm   = wid & 1;
    const int wn   = wid >> 1;
    const int quad = lane >> 4;
    const int l15  = lane & 15;

    const int b0 = blockIdx.x * 64;
    const int c  = blockIdx.y;
    const int n0 = blockIdx.z * 128;

    const int rlane = tid >> 4;       // 0..15
    const int c8    = tid & 15;       // k-chunk (8 k's)
    const int kIc   = c8 >> 2, qc = c8 & 3;
#pragma unroll
    for (int p = 0; p < 4; ++p) {
        int r = p * 16 + rlane;
        int rid_ce = center_id[b0 + r];
        int rid_cx = context_ids[(b0 + r) * CC + c];
        const float* s0 = emb + (size_t)rid_ce * 128 + c8 * 8;
        const float* s1 = emb + (size_t)rid_cx * 128 + c8 * 8;
        float4 a0 = *(const float4*)s0, a1 = *(const float4*)(s0 + 4);
        float4 b0v = *(const float4*)s1, b1v = *(const float4*)(s1 + 4);
        bf16x8 oa, ob;
        oa[0] = (short)f2bf(a0.x); oa[1] = (short)f2bf(a0.y);
        oa[2] = (short)f2bf(a0.z); oa[3] = (short)f2bf(a0.w);
        oa[4] = (short)f2bf(a1.x); oa[5] = (short)f2bf(a1.y);
        oa[6] = (short)f2bf(a1.z); oa[7] = (short)f2bf(a1.w);
        ob[0] = (short)f2bf(b0v.x); ob[1] = (short)f2bf(b0v.y);
        ob[2] = (short)f2bf(b0v.z); ob[3] = (short)f2bf(b0v.w);
        ob[4] = (short)f2bf(b1v.x); ob[5] = (short)f2bf(b1v.y);
        ob[6] = (short)f2bf(b1v.z); ob[7] = (short)f2bf(b1v.w);
        *(bf16x8*)(As + (size_t)(p * 8 + kIc) * AS_STRIDE + (qc * 16 + rlane) * 8) = oa;
        *(bf16x8*)(As + (size_t)(p * 8 + kIc + 4) * AS_STRIDE + (qc * 16 + rlane) * 8) = ob;
    }
    __syncthreads();

    float benc[4];
#pragma unroll
    for (int nt = 0; nt < 4; ++nt)
        benc[nt] = b_enc[n0 + wn * 64 + nt * 16 + l15];

    f32x4 acc[2][4];
#pragma unroll
    for (int mt = 0; mt < 2; ++mt)
#pragma unroll
        for (int nt = 0; nt < 4; ++nt) acc[mt][nt] = (f32x4){0.f, 0.f, 0.f, 0.f};

#pragma unroll
    for (int kI = 0; kI < 8; ++kI) {
        bf16x8 a[2], b[4];
#pragma unroll
        for (int mt = 0; mt < 2; ++mt)
            a[mt] = *(const bf16x8*)(As + (size_t)((wm * 2 + mt) * 8 + kI) * AS_STRIDE + lane * 8);
#pragma unroll
        for (int nt = 0; nt < 4; ++nt) {
            size_t jg = (size_t)blockIdx.z * 8 + wn * 4 + nt;
            b[nt] = *(const bf16x8*)(WeP + ((jg * 8 + kI) * 64 + lane) * 8);
        }
#pragma unroll
        for (int mt = 0; mt < 2; ++mt)
#pragma unroll
            for (int nt = 0; nt < 4; ++nt)
                acc[mt][nt] = __builtin_amdgcn_mfma_f32_16x16x32_bf16(
                    a[mt], b[nt], acc[mt][nt], 0, 0, 0);
    }

#pragma unroll
    for (int mt = 0; mt < 2; ++mt)
#pragma unroll
        for (int nt = 0; nt < 4; ++nt) {
            int col = wn * 64 + nt * 16 + l15;
#pragma unroll
            for (int reg = 0; reg < 4; ++reg) {
                int row = wm * 32 + mt * 16 + quad * 4 + reg;
                Cs[row][col] = f2bf(fmaxf(acc[mt][nt][reg] + benc[nt], 0.f));
            }
        }
    __syncthreads();
#pragma unroll
    for (int i = 0; i < 4; ++i) {
        int ch = i * 256 + tid;
        int row = ch >> 4, cc = ch & 15;
        bf16x8 v = *(const bf16x8*)&Cs[row][cc * 8];
        *(bf16x8*)(enc_relu + ((size_t)(b0 + row) * CC + c) * 256 + n0 + cc * 8) = v;
    }
}

// ---------------------------------------------------------------------------
// Kernel 2: latent heads + KL + context logits fused. 1024 blocks x 128 thr.
// Head weights from interleaved bf16 Wmv. z stays in regs; ctx dots read
// packed WvP rows. Zeroes out[0].
// ---------------------------------------------------------------------------
__global__ __launch_bounds__(128) void k_latent(
    const unsigned short* __restrict__ enc_relu, const unsigned short* __restrict__ Wmv,
    const float* __restrict__ b_mean, const float* __restrict__ b_var,
    const float* __restrict__ epsilon,
    const int* __restrict__ center_id, const int* __restrict__ context_ids,
    const unsigned short* __restrict__ WvP, const float* __restrict__ bv,
    const float* __restrict__ prior_means, const float* __restrict__ prior_vars,
    unsigned short* __restrict__ z_pack, float* __restrict__ kl,
    float* __restrict__ ctxsum, float* __restrict__ out)
{
    __shared__ __align__(16) float hs[256];
    __shared__ float red[2];
    __shared__ float credp[CC][2];
    const int tid = threadIdx.x;
    const int b = blockIdx.x;
    const int wid = tid >> 6;

    if (b == 0 && tid == 0) out[0] = 0.f;

    {
        const int j = tid * 2;
        float s0 = 0.f, s1 = 0.f;
#pragma unroll
        for (int c = 0; c < CC; ++c) {
            ushort2 u = *(const ushort2*)(enc_relu + ((size_t)b * CC + c) * 256 + j);
            s0 += bf2f(u.x); s1 += bf2f(u.y);
        }
        hs[j] = s0; hs[j + 1] = s1;
    }
    __syncthreads();

    const int d = tid;
    float m  = b_mean[d];
    float vr = b_var[d];
    for (int k0 = 0; k0 < 256; k0 += 4) {
        float4 h4 = *(const float4*)&hs[k0];
#pragma unroll
        for (int kk = 0; kk < 4; ++kk) {
            float hk = ((const float*)&h4)[kk];
            ushort2 u = *(const ushort2*)(Wmv + ((size_t)(k0 + kk) * 128 + d) * 2);
            m  += hk * bf2f(u.x);
            vr += hk * bf2f(u.y);
        }
    }

    float var = (vr > 20.f) ? vr : log1pf(__expf(vr));
    float zd = m + __expf(0.5f * var) * epsilon[d];
    unsigned short zu = f2bf(zd);
    const int kIz = d >> 5, qz = (d >> 3) & 3, ez = d & 7;
    {
        const int bg = b >> 4, l15b = b & 15;
        z_pack[(((size_t)(bg * 4 + kIz)) * 64 + qz * 16 + l15b) * 8 + ez] = zu;
    }
    float zb = bf2f(zu);

    int cid = center_id[b];
    float pm  = prior_means[(size_t)cid * 128 + d];
    float pvr = prior_vars[(size_t)cid * 128 + d];
    float pv  = (pvr > 20.f) ? pvr : log1pf(__expf(pvr));
    float diff = pm - m;
    float t = var / pv + diff * diff / pv - 1.f + logf(pv) - logf(var);
#pragma unroll
    for (int off = 32; off; off >>= 1) t += __shfl_down(t, off, 64);
    if ((tid & 63) == 0) red[wid] = t;

    int cids[CC];
#pragma unroll
    for (int p = 0; p < CC; ++p) cids[p] = context_ids[b * CC + p];
    float cs[CC];
#pragma unroll
    for (int p = 0; p < CC; ++p) {
        int vg = cids[p] >> 4, l15v = cids[p] & 15;
        float w = bf2f(WvP[(((size_t)(vg * 4 + kIz)) * 64 + qz * 16 + l15v) * 8 + ez]);
        cs[p] = zb * w;
    }
#pragma unroll
    for (int p = 0; p < CC; ++p) {
#pragma unroll
        for (int off = 32; off; off >>= 1) cs[p] += __shfl_down(cs[p], off, 64);
    }
    if ((tid & 63) == 0) {
#pragma unroll
        for (int p = 0; p < CC; ++p) credp[p][wid] = cs[p];
    }
    __syncthreads();
    if (tid == 0) {
        kl[b] = 0.5f * (red[0] + red[1]);
        float c = 0.f;
#pragma unroll
        for (int p = 0; p < CC; ++p)
            c += credp[p][0] + credp[p][1] + bv[cids[p]];
        ctxsum[b] = c;
    }
}

// ---------------------------------------------------------------------------
// Kernel 3: streaming MFMA GEMM + exp-sum. Grid (393, 4); block = 128 vocab
// x 256 batch (2 mi steps). B-fragments hoisted into registers; private
// per-block partial rows (NO cross-XCD atomics — R7 lesson: 400k contended
// device atomics cost ~100 us).
// ---------------------------------------------------------------------------
__global__ __launch_bounds__(256) void k_lse(
    const unsigned short* __restrict__ z_pack, const unsigned short* __restrict__ WvP,
    const float* __restrict__ bv, float* __restrict__ partial)
{
    __shared__ float pl[2][128][20];
    const int tid  = threadIdx.x;
    const int lane = tid & 63;
    const int wid  = tid >> 6;
    const int wm   = wid & 1;
    const int wn   = wid >> 1;
    const int quad = lane >> 4;
    const int l15  = lane & 15;
    const int n0   = blockIdx.x * 128;
    const int mg   = blockIdx.y;       // 0..3

    bf16x8 bfr[4][4];
#pragma unroll
    for (int nt = 0; nt < 4; ++nt) {
        size_t vg = (size_t)blockIdx.x * 8 + wn * 4 + nt;
#pragma unroll
        for (int kI = 0; kI < 4; ++kI)
            bfr[nt][kI] = *(const bf16x8*)(WvP + ((vg * 4 + kI) * 64 + lane) * 8);
    }

    float bvf[4];
#pragma unroll
    for (int nt = 0; nt < 4; ++nt) {
        int n = n0 + wn * 64 + nt * 16 + l15;
        bvf[nt] = (n < VV) ? bv[n] : -__builtin_huge_valf();
    }

#pragma unroll
    for (int mi = 0; mi < 2; ++mi) {
        const int mi_g = mg * 2 + mi;        // 0..7

        f32x4 acc[4][4];
#pragma unroll
        for (int mt = 0; mt < 4; ++mt)
#pragma unroll
            for (int nt = 0; nt < 4; ++nt) acc[mt][nt] = (f32x4){0.f, 0.f, 0.f, 0.f};

#pragma unroll
        for (int kI = 0; kI < 4; ++kI) {
            bf16x8 afr[4];
#pragma unroll
            for (int mt = 0; mt < 4; ++mt) {
                size_t bg = (size_t)mi_g * 8 + wm * 4 + mt;
                afr[mt] = *(const bf16x8*)(z_pack + ((bg * 4 + kI) * 64 + lane) * 8);
            }
#pragma unroll
            for (int mt = 0; mt < 4; ++mt)
#pragma unroll
                for (int nt = 0; nt < 4; ++nt)
                    acc[mt][nt] = __builtin_amdgcn_mfma_f32_16x16x32_bf16(
                        afr[mt], bfr[nt][kI], acc[mt][nt], 0, 0, 0);
        }

#pragma unroll
        for (int mt = 0; mt < 4; ++mt)
#pragma unroll
            for (int reg = 0; reg < 4; ++reg) {
                float s = 0.f;
#pragma unroll
                for (int nt = 0; nt < 4; ++nt)
                    s += __expf(acc[mt][nt][reg] + bvf[nt]);
                pl[wn][wm * 64 + mt * 16 + quad * 4 + reg][l15] = s;
            }
        __syncthreads();
        if (tid < 128) {
            const float* p0 = &pl[0][tid][0];
            const float* p1 = &pl[1][tid][0];
            float4 a0 = *(const float4*)(p0);
            float4 a1 = *(const float4*)(p0 + 4);
            float4 a2 = *(const float4*)(p0 + 8);
            float4 a3 = *(const float4*)(p0 + 12);
            float4 b0 = *(const float4*)(p1);
            float4 b1 = *(const float4*)(p1 + 4);
            float4 b2 = *(const float4*)(p1 + 8);
            float4 b3 = *(const float4*)(p1 + 12);
            float tot = (a0.x + a0.y + a0.z + a0.w) + (a1.x + a1.y + a1.z + a1.w)
                      + (a2.x + a2.y + a2.z + a2.w) + (a3.x + a3.y + a3.z + a3.w)
                      + (b0.x + b0.y + b0.z + b0.w) + (b1.x + b1.y + b1.z + b1.w)
                      + (b2.x + b2.y + b2.z + b2.w) + (b3.x + b3.y + b3.z + b3.w);
            partial[(size_t)blockIdx.x * 1024 + mi_g * 128 + tid] = tot;
        }
        __syncthreads();
    }
}

// ---------------------------------------------------------------------------
// Kernel 4: reduce partials over 393 vocab slices; final loss.
// ---------------------------------------------------------------------------
__global__ __launch_bounds__(256) void k_reduce(
    const float* __restrict__ partial, const float* __restrict__ ctxsum,
    const float* __restrict__ kl, float* __restrict__ out)
{
    __shared__ float bred[4];
    const int tid = threadIdx.x;
    const int row = blockIdx.x * 16 + (tid >> 4);
    const int part = tid & 15;

    float s = 0.f;
    for (int vb = part; vb < 393; vb += 16)
        s += partial[(size_t)vb * 1024 + row];
    s += __shfl_xor(s, 1, 64);
    s += __shfl_xor(s, 2, 64);
    s += __shfl_xor(s, 4, 64);
    s += __shfl_xor(s, 8, 64);

    float v = 0.f;
    if (part == 0)
        v = ctxsum[row] - 10.f * logf(s) - kl[row];
    v += __shfl_xor(v, 16, 64);
    v += __shfl_xor(v, 32, 64);
    if ((tid & 63) == 0) bred[tid >> 6] = v;
    __syncthreads();
    if (tid == 0)
        atomicAdd(out, (bred[0] + bred[1] + bred[2] + bred[3]) * (1.f / 1024.f));
}

// ---------------------------------------------------------------------------
extern "C" void kernel_launch(void* const* d_in, const int* in_sizes, int n_in,
                              void* d_out, int out_size, void* d_ws, size_t ws_size,
                              hipStream_t stream)
{
    const int*   center_id   = (const int*)d_in[0];
    const int*   context_ids = (const int*)d_in[1];
    const float* epsilon     = (const float*)d_in[2];
    const float* emb         = (const float*)d_in[3];
    const float* prior_means = (const float*)d_in[4];
    const float* prior_vars  = (const float*)d_in[5];
    const float* W_enc       = (const float*)d_in[6];
    const float* b_enc       = (const float*)d_in[7];
    const float* W_mean      = (const float*)d_in[8];
    const float* b_mean      = (const float*)d_in[9];
    const float* W_var       = (const float*)d_in[10];
    const float* b_var       = (const float*)d_in[11];
    const float* W_vocab     = (const float*)d_in[12];
    const float* b_vocab     = (const float*)d_in[13];

    float* out = (float*)d_out;
    char*  ws  = (char*)d_ws;

    size_t off = 0;
    unsigned short* WvP      = (unsigned short*)(ws + off); off += 12877824;  // 50304*128*2
    unsigned short* WeP      = (unsigned short*)(ws + off); off += 131072;    // 256*256*2
    unsigned short* Wmv      = (unsigned short*)(ws + off); off += 131072;    // 256*128*2*2
    unsigned short* z_pack   = (unsigned short*)(ws + off); off += 262144;    // 1024*128*2
    unsigned short* enc_relu = (unsigned short*)(ws + off); off += 5242880;   // 1024*10*256*2
    float*          kl       = (float*)(ws + off);          off += 4096;
    float*          ctxsum   = (float*)(ws + off);          off += 4096;
    float*          partial  = (float*)(ws + off);          off += 1609728;   // 393*1024*4

    k_prep<<<806, 256, 0, stream>>>(W_vocab, W_enc, W_mean, W_var, WvP, WeP, Wmv);
    k_enc<<<dim3(16, 10, 2), 256, 0, stream>>>(center_id, context_ids, emb, WeP,
                                               b_enc, enc_relu);
    k_latent<<<1024, 128, 0, stream>>>(enc_relu, Wmv, b_mean, b_var, epsilon,
                                       center_id, context_ids, WvP, b_vocab,
                                       prior_means, prior_vars, z_pack, kl,
                                       ctxsum, out);
    k_lse<<<dim3(393, 4), 256, 0, stream>>>(z_pack, WvP, b_vocab, partial);
    k_reduce<<<64, 256, 0, stream>>>(partial, ctxsum, kl, out);
}